// Round 1
// baseline (480.504 us; speedup 1.0000x reference)
//
#include <hip/hip_runtime.h>

#define IN_F 4096
#define OUT_F 4096
#define NROWS 8192   // 4*2048

typedef __attribute__((ext_vector_type(4))) float f32x4;
typedef __attribute__((ext_vector_type(8))) short bf16x8;
typedef __attribute__((ext_vector_type(8))) unsigned short u16x8;

__device__ __forceinline__ unsigned short f2bf(float f) {
  union { float f; unsigned u; } x; x.f = f;
  unsigned r = x.u + 0x7FFFu + ((x.u >> 16) & 1u);   // RNE
  return (unsigned short)(r >> 16);
}

__device__ __forceinline__ void gload_lds16(const unsigned short* g, unsigned short* l) {
  __builtin_amdgcn_global_load_lds((__attribute__((address_space(1))) void*)g,
                                   (__attribute__((address_space(3))) void*)l,
                                   16, 0, 0);
}

// in-register 16-point FWHT (4 butterfly bits); all indices compile-time after unroll
__device__ __forceinline__ void bfly16(float v[16]) {
#pragma unroll
  for (int s = 1; s < 16; s <<= 1) {
#pragma unroll
    for (int i = 0; i < 16; ++i) {
      if (!(i & s)) { float a = v[i], b = v[i + s]; v[i] = a + b; v[i + s] = a - b; }
    }
  }
}

// ---------------- 1) dequant: W_hat[o][k] = grid[Qidxs[o][k/8]][k%8]  (bf16) ----------------
__global__ __launch_bounds__(256) void dequant_kernel(const int* __restrict__ Q,
                                                      const float* __restrict__ grid,
                                                      unsigned short* __restrict__ Wb) {
  int g = blockIdx.x * 256 + threadIdx.x;        // 0 .. 4096*512-1
  int idx = Q[g];
  const f32x4* gp = (const f32x4*)(grid + idx * 8);
  f32x4 v0 = gp[0], v1 = gp[1];
  u16x8 o;
  o[0] = f2bf(v0[0]); o[1] = f2bf(v0[1]); o[2] = f2bf(v0[2]); o[3] = f2bf(v0[3]);
  o[4] = f2bf(v1[0]); o[5] = f2bf(v1[1]); o[6] = f2bf(v1[2]); o[7] = f2bf(v1[3]);
  *(u16x8*)(Wb + (size_t)g * 8) = o;
}

// ---------------- 2) fwht1: H = fwht(x*SU) -> bf16 ----------------
__global__ __launch_bounds__(256) void fwht1_kernel(const float* __restrict__ x,
                                                    const float* __restrict__ SU,
                                                    unsigned short* __restrict__ Hb) {
  __shared__ float buf[4096];
  int tid = threadIdx.x;
  size_t rbase = (size_t)blockIdx.x * IN_F;
  const f32x4* x4 = (const f32x4*)(x + rbase);
  const f32x4* su4 = (const f32x4*)SU;
  f32x4* b4 = (f32x4*)buf;
#pragma unroll
  for (int s = 0; s < 4; ++s) {
    int c = tid + 256 * s;
    f32x4 v = x4[c];
    f32x4 u = su4[c];
    v.x *= u.x; v.y *= u.y; v.z *= u.z; v.w *= u.w;
    b4[c] = v;
  }
  __syncthreads();
  float v[16];
  // phase 1: bits 0-3 (16 contiguous elems per thread)
  {
#pragma unroll
    for (int j = 0; j < 4; ++j) {
      f32x4 t4 = b4[tid * 4 + j];
      v[j*4+0] = t4.x; v[j*4+1] = t4.y; v[j*4+2] = t4.z; v[j*4+3] = t4.w;
    }
    bfly16(v);
#pragma unroll
    for (int j = 0; j < 4; ++j) {
      f32x4 t4; t4.x = v[j*4+0]; t4.y = v[j*4+1]; t4.z = v[j*4+2]; t4.w = v[j*4+3];
      b4[tid * 4 + j] = t4;
    }
  }
  __syncthreads();
  // phase 2: bits 4-7
  {
    int lo = tid & 15, hi = tid >> 4;
    int base = lo + (hi << 8);
#pragma unroll
    for (int j = 0; j < 16; ++j) v[j] = buf[base + (j << 4)];
    bfly16(v);
#pragma unroll
    for (int j = 0; j < 16; ++j) buf[base + (j << 4)] = v[j];
  }
  __syncthreads();
  // phase 3: bits 8-11, epilogue direct to global (coalesced ushort stores)
  {
#pragma unroll
    for (int j = 0; j < 16; ++j) v[j] = buf[tid + (j << 8)];
    bfly16(v);
#pragma unroll
    for (int j = 0; j < 16; ++j)
      Hb[rbase + tid + (j << 8)] = f2bf(v[j] * 0.015625f);   // 1/sqrt(4096)
  }
}

// ---------------- 3) GEMM: Y[m][o] = sum_k H[m][k] * W[o][k]  (bf16 -> fp32) ----------------
__global__ __launch_bounds__(256) void gemm_kernel(const unsigned short* __restrict__ Hb,
                                                   const unsigned short* __restrict__ Wb,
                                                   float* __restrict__ Y) {
  __shared__ unsigned short As[128 * 64];   // [128 rows][64 k] bf16
  __shared__ unsigned short Bs[128 * 64];
  int tid = threadIdx.x;
  int bid = blockIdx.x;
  int nwg = gridDim.x;                       // 2048, divisible by 8 -> bijective swizzle
  int cpx = nwg >> 3;
  int swz = (bid & 7) * cpx + (bid >> 3);
  const int nbn = OUT_F / 128;               // 32
  int brow = (swz / nbn) * 128;
  int bcol = (swz % nbn) * 128;

  int lane = tid & 63;
  int wave = tid >> 6;
  int wr = wave >> 1, wc = wave & 1;         // 2x2 waves, each owns 64x64
  int lrow = lane & 15;
  int kgrp = lane >> 4;

  f32x4 acc[4][4] = {};
  const unsigned short* Abase = Hb + (size_t)brow * IN_F;
  const unsigned short* Bbase = Wb + (size_t)bcol * IN_F;

  for (int kt = 0; kt < IN_F; kt += 64) {
    __syncthreads();
#pragma unroll
    for (int s = 0; s < 4; ++s) {
      int c = tid + 256 * s;                 // 16B chunk id, 0..1023
      int row = c >> 3;
      int ko = (c & 7) * 8;
      gload_lds16(Abase + (size_t)row * IN_F + kt + ko, As + c * 8);
      gload_lds16(Bbase + (size_t)row * IN_F + kt + ko, Bs + c * 8);
    }
    __syncthreads();                         // drains vmcnt before barrier
#pragma unroll
    for (int kk = 0; kk < 2; ++kk) {
      bf16x8 a[4], b[4];
      int kof = kk * 32 + kgrp * 8;
#pragma unroll
      for (int m = 0; m < 4; ++m)
        a[m] = *(const bf16x8*)(As + (wr * 64 + m * 16 + lrow) * 64 + kof);
#pragma unroll
      for (int n = 0; n < 4; ++n)
        b[n] = *(const bf16x8*)(Bs + (wc * 64 + n * 16 + lrow) * 64 + kof);
#pragma unroll
      for (int m = 0; m < 4; ++m)
#pragma unroll
        for (int n = 0; n < 4; ++n)
          acc[m][n] = __builtin_amdgcn_mfma_f32_16x16x32_bf16(a[m], b[n], acc[m][n], 0, 0, 0);
    }
  }
  // epilogue: C/D layout col=lane&15, row=(lane>>4)*4+r  (m89-verified)
  int orow = brow + wr * 64 + kgrp * 4;
  int ocol = bcol + wc * 64 + lrow;
#pragma unroll
  for (int m = 0; m < 4; ++m)
#pragma unroll
    for (int n = 0; n < 4; ++n) {
      float* p = Y + (size_t)(orow + m * 16) * OUT_F + (ocol + n * 16);
#pragma unroll
      for (int r = 0; r < 4; ++r)
        p[(size_t)r * OUT_F] = acc[m][n][r];
    }
}

// ---------------- 4) fwht2 (in-place on d_out) + SV + bias ----------------
__global__ __launch_bounds__(256) void fwht2_kernel(float* __restrict__ Y,
                                                    const float* __restrict__ SV,
                                                    const float* __restrict__ bias) {
  __shared__ float buf[4096];
  int tid = threadIdx.x;
  size_t rbase = (size_t)blockIdx.x * OUT_F;
  f32x4* y4 = (f32x4*)(Y + rbase);
  f32x4* b4 = (f32x4*)buf;
#pragma unroll
  for (int s = 0; s < 4; ++s) {
    int c = tid + 256 * s;
    b4[c] = y4[c];
  }
  __syncthreads();
  float v[16];
  // phase 1: bits 0-3
  {
#pragma unroll
    for (int j = 0; j < 4; ++j) {
      f32x4 t4 = b4[tid * 4 + j];
      v[j*4+0] = t4.x; v[j*4+1] = t4.y; v[j*4+2] = t4.z; v[j*4+3] = t4.w;
    }
    bfly16(v);
#pragma unroll
    for (int j = 0; j < 4; ++j) {
      f32x4 t4; t4.x = v[j*4+0]; t4.y = v[j*4+1]; t4.z = v[j*4+2]; t4.w = v[j*4+3];
      b4[tid * 4 + j] = t4;
    }
  }
  __syncthreads();
  // phase 2: bits 4-7
  {
    int lo = tid & 15, hi = tid >> 4;
    int base = lo + (hi << 8);
#pragma unroll
    for (int j = 0; j < 16; ++j) v[j] = buf[base + (j << 4)];
    bfly16(v);
#pragma unroll
    for (int j = 0; j < 16; ++j) buf[base + (j << 4)] = v[j];
  }
  __syncthreads();
  // phase 3: bits 8-11 + epilogue
  {
#pragma unroll
    for (int j = 0; j < 16; ++j) v[j] = buf[tid + (j << 8)];
    bfly16(v);
#pragma unroll
    for (int j = 0; j < 16; ++j) {
      int col = tid + (j << 8);
      Y[rbase + col] = v[j] * 0.015625f * SV[col] + bias[col];
    }
  }
}

extern "C" void kernel_launch(void* const* d_in, const int* in_sizes, int n_in,
                              void* d_out, int out_size, void* d_ws, size_t ws_size,
                              hipStream_t stream) {
  const float* x     = (const float*)d_in[0];
  const int*   Qidxs = (const int*)d_in[1];
  const float* grid  = (const float*)d_in[2];
  const float* SU    = (const float*)d_in[3];
  const float* SV    = (const float*)d_in[4];
  const float* bias  = (const float*)d_in[5];
  float* out = (float*)d_out;

  unsigned short* Wb = (unsigned short*)d_ws;                    // 4096*4096 bf16 = 33.5 MB
  unsigned short* Hb = Wb + (size_t)OUT_F * IN_F;                // 8192*4096 bf16 = 67 MB

  hipLaunchKernelGGL(dequant_kernel, dim3((OUT_F * (IN_F / 8)) / 256), dim3(256), 0, stream,
                     Qidxs, grid, Wb);
  hipLaunchKernelGGL(fwht1_kernel, dim3(NROWS), dim3(256), 0, stream, x, SU, Hb);
  hipLaunchKernelGGL(gemm_kernel, dim3((NROWS / 128) * (OUT_F / 128)), dim3(256), 0, stream,
                     Hb, Wb, out);
  hipLaunchKernelGGL(fwht2_kernel, dim3(NROWS), dim3(256), 0, stream, out, SV, bias);
}

// Round 2
// 357.238 us; speedup vs baseline: 1.3451x; 1.3451x over previous
//
#include <hip/hip_runtime.h>

#define IN_F 4096
#define OUT_F 4096
#define NROWS 8192   // 4*2048
#define BK 32
#define NT (IN_F / BK)   // 128

typedef __attribute__((ext_vector_type(4))) float f32x4;
typedef __attribute__((ext_vector_type(8))) short bf16x8;
typedef __attribute__((ext_vector_type(8))) unsigned short u16x8;

__device__ __forceinline__ unsigned short f2bf(float f) {
  union { float f; unsigned u; } x; x.f = f;
  unsigned r = x.u + 0x7FFFu + ((x.u >> 16) & 1u);   // RNE
  return (unsigned short)(r >> 16);
}

__device__ __forceinline__ void gload_lds16(const unsigned short* g, unsigned short* l) {
  __builtin_amdgcn_global_load_lds((__attribute__((address_space(1))) void*)g,
                                   (__attribute__((address_space(3))) void*)l,
                                   16, 0, 0);
}

// in-register 16-point FWHT (4 butterfly bits)
__device__ __forceinline__ void bfly16(float v[16]) {
#pragma unroll
  for (int s = 1; s < 16; s <<= 1) {
#pragma unroll
    for (int i = 0; i < 16; ++i) {
      if (!(i & s)) { float a = v[i], b = v[i + s]; v[i] = a + b; v[i + s] = a - b; }
    }
  }
}

// ---------------- 1) dequant: W_hat[o][k] = grid[Qidxs[o][k/8]][k%8]  (bf16) ----------------
__global__ __launch_bounds__(256) void dequant_kernel(const int* __restrict__ Q,
                                                      const float* __restrict__ grid,
                                                      unsigned short* __restrict__ Wb) {
  int g = blockIdx.x * 256 + threadIdx.x;        // 0 .. 4096*512-1
  int idx = Q[g];
  const f32x4* gp = (const f32x4*)(grid + idx * 8);
  f32x4 v0 = gp[0], v1 = gp[1];
  u16x8 o;
  o[0] = f2bf(v0[0]); o[1] = f2bf(v0[1]); o[2] = f2bf(v0[2]); o[3] = f2bf(v0[3]);
  o[4] = f2bf(v1[0]); o[5] = f2bf(v1[1]); o[6] = f2bf(v1[2]); o[7] = f2bf(v1[3]);
  *(u16x8*)(Wb + (size_t)g * 8) = o;
}

// ---------------- 2) fwht1: H = fwht(x*SU) -> bf16 ----------------
__global__ __launch_bounds__(256) void fwht1_kernel(const float* __restrict__ x,
                                                    const float* __restrict__ SU,
                                                    unsigned short* __restrict__ Hb) {
  __shared__ float buf[4096];
  int tid = threadIdx.x;
  size_t rbase = (size_t)blockIdx.x * IN_F;
  const f32x4* x4 = (const f32x4*)(x + rbase);
  const f32x4* su4 = (const f32x4*)SU;
  f32x4* b4 = (f32x4*)buf;
#pragma unroll
  for (int s = 0; s < 4; ++s) {
    int c = tid + 256 * s;
    f32x4 v = x4[c];
    f32x4 u = su4[c];
    v.x *= u.x; v.y *= u.y; v.z *= u.z; v.w *= u.w;
    b4[c] = v;
  }
  __syncthreads();
  float v[16];
  {
#pragma unroll
    for (int j = 0; j < 4; ++j) {
      f32x4 t4 = b4[tid * 4 + j];
      v[j*4+0] = t4.x; v[j*4+1] = t4.y; v[j*4+2] = t4.z; v[j*4+3] = t4.w;
    }
    bfly16(v);
#pragma unroll
    for (int j = 0; j < 4; ++j) {
      f32x4 t4; t4.x = v[j*4+0]; t4.y = v[j*4+1]; t4.z = v[j*4+2]; t4.w = v[j*4+3];
      b4[tid * 4 + j] = t4;
    }
  }
  __syncthreads();
  {
    int lo = tid & 15, hi = tid >> 4;
    int base = lo + (hi << 8);
#pragma unroll
    for (int j = 0; j < 16; ++j) v[j] = buf[base + (j << 4)];
    bfly16(v);
#pragma unroll
    for (int j = 0; j < 16; ++j) buf[base + (j << 4)] = v[j];
  }
  __syncthreads();
  {
#pragma unroll
    for (int j = 0; j < 16; ++j) v[j] = buf[tid + (j << 8)];
    bfly16(v);
#pragma unroll
    for (int j = 0; j < 16; ++j)
      Hb[rbase + tid + (j << 8)] = f2bf(v[j] * 0.015625f);   // 1/sqrt(4096)
  }
}

// ---------------- 3) GEMM 256x256, BK=32, 8 waves, ring-4 LDS, counted vmcnt ----------------
#define MM(i, A, B) acc[i] = __builtin_amdgcn_mfma_f32_16x16x32_bf16(A, B, acc[i], 0, 0, 0)

__global__ __launch_bounds__(512) void gemm256_kernel(const unsigned short* __restrict__ Hb,
                                                      const unsigned short* __restrict__ Wb,
                                                      float* __restrict__ Y) {
  __shared__ unsigned short lds[4][2][256 * BK];   // 4 slots x (A,B) x 16KB = 128 KiB
  const int tid = threadIdx.x;
  const int lane = tid & 63;
  const int wid = tid >> 6;        // 0..7
  const int wr = wid >> 2;         // 0..1  (M half)
  const int wc = wid & 3;          // 0..3  (N quarter)
  const int lrow = lane & 15;
  const int kgrp = lane >> 4;

  const int bid = blockIdx.x;
  const int swz = (bid & 7) * 64 + (bid >> 3);     // nwg=512, bijective XCD swizzle
  const int brow = (swz >> 4) << 8;                // 32 M-blocks
  const int bcol = (swz & 15) << 8;                // 16 N-blocks

  const unsigned short* Ab = Hb + (size_t)brow * IN_F;
  const unsigned short* Bb = Wb + (size_t)bcol * IN_F;

  // staging: thread handles chunks tid and tid+512; row stride 16B-slot swizzle
  const int r0 = tid >> 2;                          // 0..127
  const int sc = ((tid & 3) ^ (r0 & 3)) << 3;       // pre-swizzled source slot (elems)
  const unsigned short* Ag0 = Ab + (size_t)r0 * IN_F + sc;
  const unsigned short* Ag1 = Ab + (size_t)(r0 + 128) * IN_F + sc;
  const unsigned short* Bg0 = Bb + (size_t)r0 * IN_F + sc;
  const unsigned short* Bg1 = Bb + (size_t)(r0 + 128) * IN_F + sc;

#define STAGE_A(t, s) { gload_lds16(Ag0 + (t) * BK, &lds[s][0][tid * 8]); \
                        gload_lds16(Ag1 + (t) * BK, &lds[s][0][(tid + 512) * 8]); }
#define STAGE_B(t, s) { gload_lds16(Bg0 + (t) * BK, &lds[s][1][tid * 8]); \
                        gload_lds16(Bg1 + (t) * BK, &lds[s][1][(tid + 512) * 8]); }

  // swizzled fragment read: lane holds [R][kgrp*8..+7]; slot XORed by row&3
  auto fragLd = [&](const unsigned short* base, int R) -> bf16x8 {
    return *(const bf16x8*)(base + R * BK + ((kgrp ^ (R & 3)) << 3));
  };

  f32x4 acc[32] = {};   // [mf(8)][n(4)], mf = mh*4+m

  // prologue: stage T0,T1,T2 (12 loads); wait T0 resident (8 left in flight)
  STAGE_A(0, 0); STAGE_B(0, 0);
  STAGE_A(1, 1); STAGE_B(1, 1);
  STAGE_A(2, 2); STAGE_B(2, 2);
  asm volatile("s_waitcnt vmcnt(8)" ::: "memory");
  asm volatile("s_barrier" ::: "memory");

  for (int t = 0; t < NT; ++t) {
    const int s = t & 3;
    const unsigned short* As = &lds[s][0][0];
    const unsigned short* Bs = &lds[s][1][0];
    bf16x8 a0, a1, a2, a3, b0, b1, b2, b3;

    // ---- phase 0: C-quadrant mh=0 ----
    a0 = fragLd(As, wr * 128 +  0 + lrow);
    a1 = fragLd(As, wr * 128 + 16 + lrow);
    a2 = fragLd(As, wr * 128 + 32 + lrow);
    a3 = fragLd(As, wr * 128 + 48 + lrow);
    b0 = fragLd(Bs, wc * 64 +  0 + lrow);
    b1 = fragLd(Bs, wc * 64 + 16 + lrow);
    b2 = fragLd(Bs, wc * 64 + 32 + lrow);
    b3 = fragLd(Bs, wc * 64 + 48 + lrow);
    if (t + 3 < NT) STAGE_A(t + 3, (t + 3) & 3);
    asm volatile("s_barrier" ::: "memory");
    __builtin_amdgcn_s_setprio(1);
    MM( 0, a0, b0); MM( 1, a0, b1); MM( 2, a0, b2); MM( 3, a0, b3);
    MM( 4, a1, b0); MM( 5, a1, b1); MM( 6, a1, b2); MM( 7, a1, b3);
    MM( 8, a2, b0); MM( 9, a2, b1); MM(10, a2, b2); MM(11, a2, b3);
    MM(12, a3, b0); MM(13, a3, b1); MM(14, a3, b2); MM(15, a3, b3);
    __builtin_amdgcn_s_setprio(0);
    asm volatile("s_barrier" ::: "memory");

    // ---- phase 1: C-quadrant mh=1 ----
    a0 = fragLd(As, wr * 128 +  64 + lrow);
    a1 = fragLd(As, wr * 128 +  80 + lrow);
    a2 = fragLd(As, wr * 128 +  96 + lrow);
    a3 = fragLd(As, wr * 128 + 112 + lrow);
    if (t + 3 < NT) STAGE_B(t + 3, (t + 3) & 3);
    asm volatile("s_barrier" ::: "memory");
    __builtin_amdgcn_s_setprio(1);
    MM(16, a0, b0); MM(17, a0, b1); MM(18, a0, b2); MM(19, a0, b3);
    MM(20, a1, b0); MM(21, a1, b1); MM(22, a1, b2); MM(23, a1, b3);
    MM(24, a2, b0); MM(25, a2, b1); MM(26, a2, b2); MM(27, a2, b3);
    MM(28, a3, b0); MM(29, a3, b1); MM(30, a3, b2); MM(31, a3, b3);
    __builtin_amdgcn_s_setprio(0);
    // tile boundary: T(t+1) must be resident; outstanding = T(t+2),T(t+3) = 8 loads
    if (t < NT - 3)       { asm volatile("s_waitcnt vmcnt(8)" ::: "memory"); }
    else if (t == NT - 3) { asm volatile("s_waitcnt vmcnt(4)" ::: "memory"); }
    else if (t == NT - 2) { asm volatile("s_waitcnt vmcnt(0)" ::: "memory"); }
    asm volatile("s_barrier" ::: "memory");
  }

  // epilogue: C/D layout col=lane&15 (B side), row=kgrp*4+r (A side)
#pragma unroll
  for (int mf = 0; mf < 8; ++mf) {
    int grow = brow + wr * 128 + mf * 16 + kgrp * 4;
    float* yp = Y + (size_t)grow * OUT_F + bcol + wc * 64 + lrow;
#pragma unroll
    for (int r = 0; r < 4; ++r)
#pragma unroll
      for (int n = 0; n < 4; ++n)
        yp[(size_t)r * OUT_F + n * 16] = acc[mf * 4 + n][r];
  }
#undef STAGE_A
#undef STAGE_B
}

// ---------------- 4) fwht2 (in-place on d_out) + SV + bias ----------------
__global__ __launch_bounds__(256) void fwht2_kernel(float* __restrict__ Y,
                                                    const float* __restrict__ SV,
                                                    const float* __restrict__ bias) {
  __shared__ float buf[4096];
  int tid = threadIdx.x;
  size_t rbase = (size_t)blockIdx.x * OUT_F;
  f32x4* y4 = (f32x4*)(Y + rbase);
  f32x4* b4 = (f32x4*)buf;
#pragma unroll
  for (int s = 0; s < 4; ++s) {
    int c = tid + 256 * s;
    b4[c] = y4[c];
  }
  __syncthreads();
  float v[16];
  {
#pragma unroll
    for (int j = 0; j < 4; ++j) {
      f32x4 t4 = b4[tid * 4 + j];
      v[j*4+0] = t4.x; v[j*4+1] = t4.y; v[j*4+2] = t4.z; v[j*4+3] = t4.w;
    }
    bfly16(v);
#pragma unroll
    for (int j = 0; j < 4; ++j) {
      f32x4 t4; t4.x = v[j*4+0]; t4.y = v[j*4+1]; t4.z = v[j*4+2]; t4.w = v[j*4+3];
      b4[tid * 4 + j] = t4;
    }
  }
  __syncthreads();
  {
    int lo = tid & 15, hi = tid >> 4;
    int base = lo + (hi << 8);
#pragma unroll
    for (int j = 0; j < 16; ++j) v[j] = buf[base + (j << 4)];
    bfly16(v);
#pragma unroll
    for (int j = 0; j < 16; ++j) buf[base + (j << 4)] = v[j];
  }
  __syncthreads();
  {
#pragma unroll
    for (int j = 0; j < 16; ++j) v[j] = buf[tid + (j << 8)];
    bfly16(v);
#pragma unroll
    for (int j = 0; j < 16; ++j) {
      int col = tid + (j << 8);
      Y[rbase + col] = v[j] * 0.015625f * SV[col] + bias[col];
    }
  }
}

extern "C" void kernel_launch(void* const* d_in, const int* in_sizes, int n_in,
                              void* d_out, int out_size, void* d_ws, size_t ws_size,
                              hipStream_t stream) {
  const float* x     = (const float*)d_in[0];
  const int*   Qidxs = (const int*)d_in[1];
  const float* grid  = (const float*)d_in[2];
  const float* SU    = (const float*)d_in[3];
  const float* SV    = (const float*)d_in[4];
  const float* bias  = (const float*)d_in[5];
  float* out = (float*)d_out;

  unsigned short* Wb = (unsigned short*)d_ws;                    // 4096*4096 bf16 = 33.5 MB
  unsigned short* Hb = Wb + (size_t)OUT_F * IN_F;                // 8192*4096 bf16 = 67 MB

  hipLaunchKernelGGL(dequant_kernel, dim3((OUT_F * (IN_F / 8)) / 256), dim3(256), 0, stream,
                     Qidxs, grid, Wb);
  hipLaunchKernelGGL(fwht1_kernel, dim3(NROWS), dim3(256), 0, stream, x, SU, Hb);
  hipLaunchKernelGGL(gemm256_kernel, dim3((NROWS / 256) * (OUT_F / 256)), dim3(512), 0, stream,
                     Hb, Wb, out);
  hipLaunchKernelGGL(fwht2_kernel, dim3(NROWS), dim3(256), 0, stream, out, SV, bias);
}